// Round 1
// baseline (313.228 us; speedup 1.0000x reference)
//
#include <hip/hip_runtime.h>

#define NEG_SLOPE 0.01f

constexpr int N = 8192;
constexpr int D = 64;
constexpr int ROWS_PER_WAVE = 8;
constexpr int WAVES = 4;
constexpr int ROWS_PER_BLOCK = ROWS_PER_WAVE * WAVES;  // 32
constexpr int TJ = 128;    // j-tile
constexpr int XPAD = 68;   // dwords per x row in LDS (68*4=272B, 16B aligned, odd-ish bank rotate)
constexpr int EPAD = 12;   // 8 e-values + 4 pad dwords (48B rows, 16B aligned)

// ---------------- Kernel A: s1/s2 + global max(s1) ----------------
// s1[i] = x[i]·w1 + c1, w1 = W^T a1, c1 = b·a1  (same for 2)
__global__ __launch_bounds__(256) void gat_prep(
    const float* __restrict__ x, const float* __restrict__ W,
    const float* __restrict__ b, const float* __restrict__ a,
    float* __restrict__ s1, float* __restrict__ s2,
    unsigned int* __restrict__ maxkey) {
  __shared__ float w1s[D], w2s[D], cs[2];
  const int t = threadIdx.x;
  if (t < 128) {
    const int sel = t >> 6, d = t & 63;
    const float* av = a + sel * D;
    float acc = 0.f;
#pragma unroll
    for (int k = 0; k < D; ++k) acc += W[k * D + d] * av[k];
    (sel ? w2s : w1s)[d] = acc;
  }
  if (t == 128 || t == 129) {
    const int sel = t - 128;
    float acc = 0.f;
    for (int d = 0; d < D; ++d) acc += b[d] * a[sel * D + d];
    cs[sel] = acc;
  }
  __syncthreads();

  const int i = blockIdx.x * 256 + t;
  const float4* xr = (const float4*)(x + (size_t)i * D);
  float v1 = cs[0], v2 = cs[1];
#pragma unroll
  for (int k = 0; k < 16; ++k) {
    float4 v = xr[k];
    v1 += v.x * w1s[4 * k + 0] + v.y * w1s[4 * k + 1] + v.z * w1s[4 * k + 2] + v.w * w1s[4 * k + 3];
    v2 += v.x * w2s[4 * k + 0] + v.y * w2s[4 * k + 1] + v.z * w2s[4 * k + 2] + v.w * w2s[4 * k + 3];
  }
  s1[i] = v1;
  s2[i] = v2;

  // wave-reduce max(s1), one atomic per wave (monotone f32->u32 key)
  float m = v1;
#pragma unroll
  for (int off = 32; off; off >>= 1) m = fmaxf(m, __shfl_xor(m, off, 64));
  if ((t & 63) == 0) {
    unsigned int bb = __float_as_uint(m);
    unsigned int key = (bb & 0x80000000u) ? ~bb : (bb | 0x80000000u);
    atomicMax(maxkey, key);
  }
}

// ---------------- Kernel C: fused softmax-weighted aggregation ----------------
__global__ __launch_bounds__(256, 2) void gat_main(
    const float* __restrict__ x, const float* __restrict__ s1g,
    const float* __restrict__ s2g, const unsigned int* __restrict__ maxkey,
    float* __restrict__ out) {
  __shared__ float xt[TJ][XPAD];
  __shared__ float et[WAVES][TJ][EPAD];

  const int t = threadIdx.x;
  const int lane = t & 63;
  const int w = t >> 6;
  const int ibase = blockIdx.x * ROWS_PER_BLOCK + w * ROWS_PER_WAVE;

  // decode global max(s1)
  const unsigned int key = *maxkey;
  const unsigned int mb = (key & 0x80000000u) ? (key ^ 0x80000000u) : ~key;
  const float maxs1 = __uint_as_float(mb);

  float s2v[ROWS_PER_WAVE], mneg[ROWS_PER_WAVE];
#pragma unroll
  for (int r = 0; r < ROWS_PER_WAVE; ++r) {
    s2v[r] = s2g[ibase + r];
    const float tt = s2v[r] + maxs1;
    mneg[r] = -fmaxf(tt, NEG_SLOPE * tt);  // -m_i (leaky is monotone)
  }

  float acc[ROWS_PER_WAVE];
  float z[ROWS_PER_WAVE];
#pragma unroll
  for (int r = 0; r < ROWS_PER_WAVE; ++r) { acc[r] = 0.f; z[r] = 0.f; }

  for (int jt = 0; jt < N / TJ; ++jt) {
    const int jbase = jt * TJ;
    // ---- stage x tile (perfectly coalesced; 8 float4 per thread) ----
#pragma unroll
    for (int c = 0; c < 8; ++c) {
      const int idx = c * 256 + t;
      const int j = idx >> 4, k = idx & 15;
      const float4 v = *(const float4*)(x + (size_t)(jbase + j) * D + 4 * k);
      *(float4*)&xt[j][4 * k] = v;
    }
    // ---- compute e-tile: lane jj-parallel, f32 exp, Z in registers ----
    float s1v[2];
    s1v[0] = s1g[jbase + lane];
    s1v[1] = s1g[jbase + 64 + lane];
#pragma unroll
    for (int c = 0; c < 2; ++c) {
#pragma unroll
      for (int rq = 0; rq < 2; ++rq) {
        float4 p;
        float* pp = &p.x;
#pragma unroll
        for (int q = 0; q < 4; ++q) {
          const int r = rq * 4 + q;
          const float tt = s2v[r] + s1v[c];
          const float lr = fmaxf(tt, NEG_SLOPE * tt);
          const float pv = __expf(lr + mneg[r]);
          z[r] += pv;
          pp[q] = pv;
        }
        *(float4*)&et[w][c * 64 + lane][rq * 4] = p;
      }
    }
    __syncthreads();
    // ---- accumulate: lane = dim; uniform-address b128 broadcasts of e ----
#pragma unroll 4
    for (int jj = 0; jj < TJ; ++jj) {
      const float xv = xt[jj][lane];
      const float4 e0 = *(const float4*)&et[w][jj][0];
      const float4 e1 = *(const float4*)&et[w][jj][4];
      acc[0] = fmaf(e0.x, xv, acc[0]);
      acc[1] = fmaf(e0.y, xv, acc[1]);
      acc[2] = fmaf(e0.z, xv, acc[2]);
      acc[3] = fmaf(e0.w, xv, acc[3]);
      acc[4] = fmaf(e1.x, xv, acc[4]);
      acc[5] = fmaf(e1.y, xv, acc[5]);
      acc[6] = fmaf(e1.z, xv, acc[6]);
      acc[7] = fmaf(e1.w, xv, acc[7]);
    }
    __syncthreads();
  }

  // reduce Z across lanes (each lane covered jj = lane and lane+64 per tile)
#pragma unroll
  for (int r = 0; r < ROWS_PER_WAVE; ++r) {
    float zz = z[r];
#pragma unroll
    for (int off = 32; off; off >>= 1) zz += __shfl_xor(zz, off, 64);
    const float inv = 1.0f / zz;
    out[(size_t)(ibase + r) * D + lane] = acc[r] * inv;
  }
}

extern "C" void kernel_launch(void* const* d_in, const int* in_sizes, int n_in,
                              void* d_out, int out_size, void* d_ws, size_t ws_size,
                              hipStream_t stream) {
  const float* x = (const float*)d_in[0];   // 8192*64
  const float* W = (const float*)d_in[1];   // 64*64
  const float* b = (const float*)d_in[2];   // 64
  const float* a = (const float*)d_in[3];   // 128

  // workspace layout: [0] u32 max key (16B slot); then s1[8192], s2[8192]
  unsigned int* maxkey = (unsigned int*)d_ws;
  float* s1 = (float*)d_ws + 16;
  float* s2 = s1 + N;
  float* out = (float*)d_out;

  hipMemsetAsync(d_ws, 0, 16, stream);  // key 0 == -inf sentinel
  gat_prep<<<N / 256, 256, 0, stream>>>(x, W, b, a, s1, s2, maxkey);
  gat_main<<<N / ROWS_PER_BLOCK, 256, 0, stream>>>(x, s1, s2, maxkey, out);
}

// Round 3
// 244.091 us; speedup vs baseline: 1.2832x; 1.2832x over previous
//
#include <hip/hip_runtime.h>

#define NEG_SLOPE 0.01f

constexpr int N = 8192;
constexpr int D = 64;
constexpr int R = 16;     // rows per block (all waves share these rows)
constexpr int W = 4;      // waves per block
constexpr int CJ = 32;    // j-chunk per wave iteration
constexpr int EP = 20;    // et row pitch (dwords): 16 e + 4 pad

// ---------------- Kernel A: s1/s2 + global max(s1) ----------------
// s1[i] = x[i]·w1 + c1, w1 = W^T a1, c1 = b·a1  (same for 2)
__global__ __launch_bounds__(256) void gat_prep(
    const float* __restrict__ x, const float* __restrict__ W_,
    const float* __restrict__ b, const float* __restrict__ a,
    float* __restrict__ s1, float* __restrict__ s2,
    unsigned int* __restrict__ maxkey) {
  __shared__ float w1s[D], w2s[D], cs[2];
  const int t = threadIdx.x;
  if (t < 128) {
    const int sel = t >> 6, d = t & 63;
    const float* av = a + sel * D;
    float acc = 0.f;
#pragma unroll
    for (int k = 0; k < D; ++k) acc += W_[k * D + d] * av[k];
    (sel ? w2s : w1s)[d] = acc;
  }
  if (t == 128 || t == 129) {
    const int sel = t - 128;
    float acc = 0.f;
    for (int d = 0; d < D; ++d) acc += b[d] * a[sel * D + d];
    cs[sel] = acc;
  }
  __syncthreads();

  const int i = blockIdx.x * 256 + t;
  const float4* xr = (const float4*)(x + (size_t)i * D);
  float v1 = cs[0], v2 = cs[1];
#pragma unroll
  for (int k = 0; k < 16; ++k) {
    float4 v = xr[k];
    v1 += v.x * w1s[4 * k + 0] + v.y * w1s[4 * k + 1] + v.z * w1s[4 * k + 2] + v.w * w1s[4 * k + 3];
    v2 += v.x * w2s[4 * k + 0] + v.y * w2s[4 * k + 1] + v.z * w2s[4 * k + 2] + v.w * w2s[4 * k + 3];
  }
  s1[i] = v1;
  s2[i] = v2;

  float m = v1;
#pragma unroll
  for (int off = 32; off; off >>= 1) m = fmaxf(m, __shfl_xor(m, off, 64));
  if ((t & 63) == 0) {
    unsigned int bb = __float_as_uint(m);
    unsigned int key = (bb & 0x80000000u) ? ~bb : (bb | 0x80000000u);
    atomicMax(maxkey, key);
  }
}

// ---------------- Kernel C: fused softmax-weighted aggregation ----------------
// Block: 16 rows, 4 waves j-split. Wave-private chunks: x in VGPRs (global,
// L2-resident), e through wave-private LDS broadcast. No barriers in main loop.
__global__ __launch_bounds__(256, 2) void gat_main(
    const float* __restrict__ x, const float* __restrict__ s1g,
    const float* __restrict__ s2g, const unsigned int* __restrict__ maxkey,
    float* __restrict__ out) {
  __shared__ float et[W][CJ][EP];     // 10 KB, wave-private e tiles
  __shared__ float accT[W][R][64];    // 16 KB, epilogue only
  __shared__ float zt[W][R];          // epilogue only

  const int t = threadIdx.x;
  const int lane = t & 63;
  const int w = t >> 6;
  const int rh = lane >> 5;           // which 8-row half this lane computes e for
  const int jj = lane & 31;
  const int ibase = blockIdx.x * R;

  // decode global max(s1)
  const unsigned int key = *maxkey;
  const unsigned int mb = (key & 0x80000000u) ? (key ^ 0x80000000u) : ~key;
  const float maxs1 = __uint_as_float(mb);

  // per-lane-half row constants (compile-time indexed, runtime cndmask select)
  float ss[8], mm[8];
#pragma unroll
  for (int q = 0; q < 8; ++q) {
    const float sA = s2g[ibase + q];
    const float sB = s2g[ibase + 8 + q];
    const float tA = sA + maxs1, tB = sB + maxs1;
    const float mA = -fmaxf(tA, NEG_SLOPE * tA);
    const float mB = -fmaxf(tB, NEG_SLOPE * tB);
    ss[q] = rh ? sB : sA;
    mm[q] = rh ? mB : mA;
  }

  float acc[R];
  float zz[8];
#pragma unroll
  for (int r = 0; r < R; ++r) acc[r] = 0.f;
#pragma unroll
  for (int q = 0; q < 8; ++q) zz[q] = 0.f;

  for (int c = w; c < N / CJ; c += W) {
    const int jbase = c * CJ;

    // ---- x chunk -> registers (coalesced, L2-resident) ----
    float xv[CJ];
#pragma unroll
    for (int k = 0; k < CJ; ++k) xv[k] = x[(size_t)(jbase + k) * D + lane];

    // ---- e chunk: lane jj covers 8 rows of its half ----
    const float s1v = s1g[jbase + jj];
    float ev[8];
#pragma unroll
    for (int q = 0; q < 8; ++q) {
      const float tt = ss[q] + s1v;
      const float lr = fmaxf(tt, NEG_SLOPE * tt);
      ev[q] = __expf(lr + mm[q]);
      zz[q] += ev[q];
    }
    *(float4*)&et[w][jj][rh * 8 + 0] = make_float4(ev[0], ev[1], ev[2], ev[3]);
    *(float4*)&et[w][jj][rh * 8 + 4] = make_float4(ev[4], ev[5], ev[6], ev[7]);

    // ---- FMA: e broadcast from own wave's LDS tile, x from registers ----
#pragma unroll
    for (int k = 0; k < CJ; ++k) {
      const float4 e0 = *(const float4*)&et[w][k][0];
      const float4 e1 = *(const float4*)&et[w][k][4];
      const float4 e2 = *(const float4*)&et[w][k][8];
      const float4 e3 = *(const float4*)&et[w][k][12];
      const float xk = xv[k];
      acc[0]  = fmaf(e0.x, xk, acc[0]);
      acc[1]  = fmaf(e0.y, xk, acc[1]);
      acc[2]  = fmaf(e0.z, xk, acc[2]);
      acc[3]  = fmaf(e0.w, xk, acc[3]);
      acc[4]  = fmaf(e1.x, xk, acc[4]);
      acc[5]  = fmaf(e1.y, xk, acc[5]);
      acc[6]  = fmaf(e1.z, xk, acc[6]);
      acc[7]  = fmaf(e1.w, xk, acc[7]);
      acc[8]  = fmaf(e2.x, xk, acc[8]);
      acc[9]  = fmaf(e2.y, xk, acc[9]);
      acc[10] = fmaf(e2.z, xk, acc[10]);
      acc[11] = fmaf(e2.w, xk, acc[11]);
      acc[12] = fmaf(e3.x, xk, acc[12]);
      acc[13] = fmaf(e3.y, xk, acc[13]);
      acc[14] = fmaf(e3.z, xk, acc[14]);
      acc[15] = fmaf(e3.w, xk, acc[15]);
    }
  }

  // ---- epilogue: wave-local z reduce, then cross-wave combine ----
#pragma unroll
  for (int q = 0; q < 8; ++q) {
#pragma unroll
    for (int off = 16; off; off >>= 1) zz[q] += __shfl_xor(zz[q], off, 64);
  }
  if (jj == 0) {  // lane 0 (rows 0..7) and lane 32 (rows 8..15)
#pragma unroll
    for (int q = 0; q < 8; ++q) zt[w][rh * 8 + q] = zz[q];
  }
#pragma unroll
  for (int r = 0; r < R; ++r) accT[w][r][lane] = acc[r];
  __syncthreads();

#pragma unroll
  for (int k = 0; k < 4; ++k) {
    const int r = (t >> 6) * 4 + k;
    const float s = accT[0][r][lane] + accT[1][r][lane] + accT[2][r][lane] + accT[3][r][lane];
    const float z = zt[0][r] + zt[1][r] + zt[2][r] + zt[3][r];
    out[(size_t)(ibase + r) * D + lane] = s / z;
  }
}

extern "C" void kernel_launch(void* const* d_in, const int* in_sizes, int n_in,
                              void* d_out, int out_size, void* d_ws, size_t ws_size,
                              hipStream_t stream) {
  const float* x = (const float*)d_in[0];   // 8192*64
  const float* W = (const float*)d_in[1];   // 64*64
  const float* b = (const float*)d_in[2];   // 64
  const float* a = (const float*)d_in[3];   // 128

  unsigned int* maxkey = (unsigned int*)d_ws;
  float* s1 = (float*)d_ws + 16;
  float* s2 = s1 + N;
  float* out = (float*)d_out;

  hipMemsetAsync(d_ws, 0, 16, stream);
  gat_prep<<<N / 256, 256, 0, stream>>>(x, W, b, a, s1, s2, maxkey);
  gat_main<<<N / R, 256, 0, stream>>>(x, s1, s2, maxkey, out);
}

// Round 5
// 96.228 us; speedup vs baseline: 3.2551x; 2.5366x over previous
//
#include <hip/hip_runtime.h>

#define NEG_SLOPE 0.01f

constexpr int N = 8192;
constexpr int D = 64;

typedef __bf16 bf16x8 __attribute__((ext_vector_type(8)));
typedef float f32x4 __attribute__((ext_vector_type(4)));

// ---------------- Kernel A: s1/s2 + global max(s1) ----------------
// s1[i] = x[i]·w1 + c1, w1 = W^T a1, c1 = b·a1  (same for 2)
__global__ __launch_bounds__(256) void gat_prep(
    const float* __restrict__ x, const float* __restrict__ W_,
    const float* __restrict__ b, const float* __restrict__ a,
    float* __restrict__ s1, float* __restrict__ s2,
    unsigned int* __restrict__ maxkey) {
  __shared__ float w1s[D], w2s[D], cs[2];
  const int t = threadIdx.x;
  if (t < 128) {
    const int sel = t >> 6, d = t & 63;
    const float* av = a + sel * D;
    float acc = 0.f;
#pragma unroll
    for (int k = 0; k < D; ++k) acc += W_[k * D + d] * av[k];
    (sel ? w2s : w1s)[d] = acc;
  }
  if (t == 128 || t == 129) {
    const int sel = t - 128;
    float acc = 0.f;
    for (int d = 0; d < D; ++d) acc += b[d] * a[sel * D + d];
    cs[sel] = acc;
  }
  __syncthreads();

  const int i = blockIdx.x * 256 + t;
  const float4* xr = (const float4*)(x + (size_t)i * D);
  float v1 = cs[0], v2 = cs[1];
#pragma unroll
  for (int k = 0; k < 16; ++k) {
    float4 v = xr[k];
    v1 += v.x * w1s[4 * k + 0] + v.y * w1s[4 * k + 1] + v.z * w1s[4 * k + 2] + v.w * w1s[4 * k + 3];
    v2 += v.x * w2s[4 * k + 0] + v.y * w2s[4 * k + 1] + v.z * w2s[4 * k + 2] + v.w * w2s[4 * k + 3];
  }
  s1[i] = v1;
  s2[i] = v2;

  float m = v1;
#pragma unroll
  for (int off = 32; off; off >>= 1) m = fmaxf(m, __shfl_xor(m, off, 64));
  if ((t & 63) == 0) {
    unsigned int bb = __float_as_uint(m);
    unsigned int key = (bb & 0x80000000u) ? ~bb : (bb | 0x80000000u);
    atomicMax(maxkey, key);
  }
}

// ---------------- Kernel B: pack x into bf16 MFMA B-fragments ----------------
// xf[gid] with gid = (window<<8) | (dtile<<6) | lane holds
//   { bf16 x[window*32 + (lane>>4)*8 + q][dtile*16 + (lane&15)] } for q=0..7
// so gat_main's B-frag load is ONE coalesced global_load_dwordx4.
__global__ __launch_bounds__(256) void gat_pack(
    const float* __restrict__ x, bf16x8* __restrict__ xf) {
  const int gid = blockIdx.x * 256 + threadIdx.x;
  const int lane = gid & 63;
  const int dt = (gid >> 6) & 3;
  const int wi = gid >> 8;
  const int jb = wi * 32 + ((lane >> 4) << 3);
  const int col = dt * 16 + (lane & 15);
  bf16x8 f;
#pragma unroll
  for (int q = 0; q < 8; ++q) f[q] = (__bf16)x[(size_t)(jb + q) * D + col];
  xf[gid] = f;
}

// ---------------- Kernel C: MFMA flash aggregation ----------------
// Block: 16 output rows; 4 waves split the j-range; no LDS in main loop.
// Per wave per 32-j window: compute P-frag in regs (8 exp), load 4 B-frags
// (coalesced dwordx4, L2-resident), 4x mfma_f32_16x16x32_bf16. Z in f32 regs.
__global__ __launch_bounds__(256, 2) void gat_main(
    const bf16x8* __restrict__ xf, const float* __restrict__ s1g,
    const float* __restrict__ s2g, const unsigned int* __restrict__ maxkey,
    float* __restrict__ out) {
  __shared__ float accT[4][16][64];
  __shared__ float zt[4][16];

  const int t = threadIdx.x;
  const int lane = t & 63;
  const int w = t >> 6;
  const int arow = lane & 15;   // A-frag M index (i within tile)
  const int grp = lane >> 4;    // k-group
  const int ibase = blockIdx.x * 16;

  // decode global max(s1)
  const unsigned int key = *maxkey;
  const unsigned int mb = (key & 0x80000000u) ? (key ^ 0x80000000u) : ~key;
  const float maxs1 = __uint_as_float(mb);

  const float s2v = s2g[ibase + arow];
  const float tmax = s2v + maxs1;
  const float mneg = -fmaxf(tmax, NEG_SLOPE * tmax);  // -m_i (leaky monotone)

  f32x4 acc0 = {0.f, 0.f, 0.f, 0.f};
  f32x4 acc1 = {0.f, 0.f, 0.f, 0.f};
  f32x4 acc2 = {0.f, 0.f, 0.f, 0.f};
  f32x4 acc3 = {0.f, 0.f, 0.f, 0.f};
  float zz = 0.f;

#pragma unroll 2
  for (int c = w; c < N / 32; c += 4) {
    // B-frags: one dwordx4 each, fully coalesced
    const int fb = c << 8;
    bf16x8 xb0 = xf[fb + 0 * 64 + lane];
    bf16x8 xb1 = xf[fb + 1 * 64 + lane];
    bf16x8 xb2 = xf[fb + 2 * 64 + lane];
    bf16x8 xb3 = xf[fb + 3 * 64 + lane];

    // s1 for this lane's 8 k-slots (L1-hot)
    const float* s1p = s1g + c * 32 + grp * 8;
    const float4 sa = *(const float4*)s1p;
    const float4 sb = *(const float4*)(s1p + 4);

    // P-frag: 8 exp in f32, cast to bf16; Z from f32 values (RNE unbiased)
    float pv[8];
    {
      const float* sv = &sa.x;
#pragma unroll
      for (int q = 0; q < 4; ++q) {
        const float tt = s2v + sv[q];
        pv[q] = __expf(fmaxf(tt, NEG_SLOPE * tt) + mneg);
      }
      const float* sw = &sb.x;
#pragma unroll
      for (int q = 0; q < 4; ++q) {
        const float tt = s2v + sw[q];
        pv[4 + q] = __expf(fmaxf(tt, NEG_SLOPE * tt) + mneg);
      }
    }
    bf16x8 pa;
#pragma unroll
    for (int q = 0; q < 8; ++q) {
      pa[q] = (__bf16)pv[q];
      zz += pv[q];
    }

    acc0 = __builtin_amdgcn_mfma_f32_16x16x32_bf16(pa, xb0, acc0, 0, 0, 0);
    acc1 = __builtin_amdgcn_mfma_f32_16x16x32_bf16(pa, xb1, acc1, 0, 0, 0);
    acc2 = __builtin_amdgcn_mfma_f32_16x16x32_bf16(pa, xb2, acc2, 0, 0, 0);
    acc3 = __builtin_amdgcn_mfma_f32_16x16x32_bf16(pa, xb3, acc3, 0, 0, 0);
  }

  // Z: sum the 4 k-group lanes of each row
  zz += __shfl_xor(zz, 16, 64);
  zz += __shfl_xor(zz, 32, 64);
  if (lane < 16) zt[w][lane] = zz;

  // C/D frag -> LDS: out-row = grp*4+reg, out-col = dt*16 + (lane&15)
#pragma unroll
  for (int reg = 0; reg < 4; ++reg) {
    accT[w][grp * 4 + reg][0 * 16 + arow] = acc0[reg];
    accT[w][grp * 4 + reg][1 * 16 + arow] = acc1[reg];
    accT[w][grp * 4 + reg][2 * 16 + arow] = acc2[reg];
    accT[w][grp * 4 + reg][3 * 16 + arow] = acc3[reg];
  }
  __syncthreads();

#pragma unroll
  for (int k = 0; k < 4; ++k) {
    const int r = w * 4 + k;
    const float s = accT[0][r][lane] + accT[1][r][lane] + accT[2][r][lane] + accT[3][r][lane];
    const float z = zt[0][r] + zt[1][r] + zt[2][r] + zt[3][r];
    out[(size_t)(ibase + r) * D + lane] = s / z;
  }
}

extern "C" void kernel_launch(void* const* d_in, const int* in_sizes, int n_in,
                              void* d_out, int out_size, void* d_ws, size_t ws_size,
                              hipStream_t stream) {
  const float* x = (const float*)d_in[0];   // 8192*64 f32
  const float* W = (const float*)d_in[1];   // 64*64
  const float* b = (const float*)d_in[2];   // 64
  const float* a = (const float*)d_in[3];   // 128

  // ws layout: [0,64B) maxkey | s1[8192] | s2[8192] | @1MB: xf (1MB bf16 frags)
  unsigned int* maxkey = (unsigned int*)d_ws;
  float* s1 = (float*)d_ws + 16;
  float* s2 = s1 + N;
  bf16x8* xf = (bf16x8*)((char*)d_ws + (1u << 20));
  float* out = (float*)d_out;

  hipMemsetAsync(d_ws, 0, 16, stream);  // key 0 == -inf sentinel
  gat_prep<<<N / 256, 256, 0, stream>>>(x, W, b, a, s1, s2, maxkey);
  gat_pack<<<(N / 32) * 4 * 64 / 256, 256, 0, stream>>>(x, xf);
  gat_main<<<N / 16, 256, 0, stream>>>(xf, s1, s2, maxkey, out);
}